// Round 3
// baseline (1749.671 us; speedup 1.0000x reference)
//
#include <hip/hip_runtime.h>
#include <math.h>

#define ND  256    // num_data (steps)
#define SEQ 2048
#define NI  256
#define NH  1024
#define NO  256

#define RB   64                 // recur blocks (1/CU, all co-resident)
#define RT   1024               // 16 waves
#define HPB  16                 // hidden units per block
#define NHP  1028               // padded LDS row: 16B-aligned (1028*4%16==0), +4 bank shift/row

#define XTB  32                 // t-tile for xproj
#define OTB  8                  // t-tile for outproj

// relaxed agent-scope atomics: bypass L1/L2 to the device coherence point (IF)
#define AL(p)    __hip_atomic_load((p), __ATOMIC_RELAXED, __HIP_MEMORY_SCOPE_AGENT)
#define AS(p,v)  __hip_atomic_store((p), (v), __ATOMIC_RELAXED, __HIP_MEMORY_SCOPE_AGENT)

// ---------------- input projections, t-tiled: X[t][h] = b[h] + x[t,2047,:]@W --
__global__ void xproj(const float* __restrict__ x,
                      const float* __restrict__ Win1, const float* __restrict__ b1,
                      const float* __restrict__ Win2, const float* __restrict__ b2,
                      float* __restrict__ X1, float* __restrict__ X2) {
    const int   layer = blockIdx.z;
    const int   t0    = blockIdx.y * XTB;
    const int   h     = blockIdx.x * 256 + threadIdx.x;
    const float* W = layer ? Win2 : Win1;
    const float* b = layer ? b2   : b1;
    float*       X = layer ? X2   : X1;

    __shared__ float lx[XTB][NI];          // 32 KB
    for (int idx = threadIdx.x; idx < XTB * NI; idx += 256) {
        int r = idx >> 8, c = idx & (NI - 1);
        lx[r][c] = x[(size_t)(t0 + r) * SEQ * NI + (size_t)(SEQ - 1) * NI + c];
    }
    __syncthreads();

    float acc[XTB];
    float bias = b[h];
    #pragma unroll
    for (int r = 0; r < XTB; ++r) acc[r] = bias;

    for (int i = 0; i < NI; ++i) {
        float wv = W[i * NH + h];
        #pragma unroll
        for (int r = 0; r < XTB; ++r) acc[r] += lx[r][i] * wv;
    }
    #pragma unroll
    for (int r = 0; r < XTB; ++r) X[(t0 + r) * NH + h] = acc[r];
}

// ---------------- sequential recurrence: tag-in-mantissa dataflow, no barrier -
// Exchanged word = fp32 value with low 2 mantissa bits replaced by (step&3).
// Consumer polls until tag matches; the successful poll IS the data load.
// Depth-2 ping-pong is overwrite-safe: a producer reaching step u+1 proves all
// blocks passed sync(u-1), hence fully staged the slot being overwritten.
__launch_bounds__(RT, 1)
__global__ void recur(const float* __restrict__ Wr1, const float* __restrict__ Wr2,
                      const float* __restrict__ X1,  const float* __restrict__ X2,
                      unsigned* ZB, unsigned* Z2B, float* Z1hist) {
    __shared__ float lW1[HPB][NHP];        // ~65.8 KB
    __shared__ float lW2[HPB][NHP];        // ~65.8 KB
    __shared__ float sz [2][NH];           // 8 KB  z12 staging (ping-pong)
    __shared__ float sz2[NH];              // 4 KB  z2 staging (2-step cadence)

    const int tid = threadIdx.x;
    const int h0  = blockIdx.x * HPB;

    for (int idx = tid; idx < HPB * NH; idx += RT) {
        int hw = idx & (HPB - 1);
        int k  = idx >> 4;
        lW1[hw][k] = Wr1[(size_t)k * NH + h0 + hw];
        lW2[hw][k] = Wr2[(size_t)k * NH + h0 + hw];
    }
    __syncthreads();

    const int w = tid >> 6;                // wave <-> hidden unit
    const int l = tid & 63;
    const int h = h0 + w;

    float z2h = 0.0f;                      // lane0-owned z2[h] register state

    for (int t = 0; t < ND; ++t) {
        const bool even = (t & 1) == 0;

        // independent cached loads — latency hidden under the poll
        float xv1 = X1[t * NH + h];
        float xv2 = even ? X2[t * NH + h] : 0.0f;

        // ---- poll own element until step-tag matches (data arrives with it)
        unsigned tg1 = (unsigned)t & 3u;
        unsigned* p1 = ZB + (t & 1) * NH + tid;
        unsigned wv;
        if (even) {
            unsigned tg2 = (unsigned)(t >> 1) & 3u;
            unsigned* p2 = Z2B + ((t >> 1) & 1) * NH + tid;
            unsigned yv;
            do { wv = AL(p1); yv = AL(p2); }
            while ((((wv ^ tg1) & 3u) | ((yv ^ tg2) & 3u)) != 0u);
            sz2[tid] = __uint_as_float(yv);
        } else {
            do { wv = AL(p1); } while ((wv & 3u) != tg1);
        }
        sz[t & 1][tid] = __uint_as_float(wv);
        __syncthreads();                   // the only sync per step

        // ---- dot products via ds_read_b128 fragments (k = 16*l + j)
        const float4* zv  = (const float4*)sz[t & 1];
        const float4* wv1 = (const float4*)(&lW1[w][0]);
        float r1 = 0.0f, r2 = 0.0f;
        #pragma unroll
        for (int jj = 0; jj < 4; ++jj) {
            float4 a = zv[4 * l + jj], bq = wv1[4 * l + jj];
            r1 += a.x * bq.x + a.y * bq.y + a.z * bq.z + a.w * bq.w;
        }
        if (even) {
            const float4* z2v = (const float4*)sz2;
            const float4* wv2 = (const float4*)(&lW2[w][0]);
            #pragma unroll
            for (int jj = 0; jj < 4; ++jj) {
                float4 a = z2v[4 * l + jj], bq = wv2[4 * l + jj];
                r2 += a.x * bq.x + a.y * bq.y + a.z * bq.z + a.w * bq.w;
            }
            #pragma unroll
            for (int off = 32; off; off >>= 1) {
                r1 += __shfl_xor(r1, off, 64);
                r2 += __shfl_xor(r2, off, 64);
            }
        } else {
            #pragma unroll
            for (int off = 32; off; off >>= 1)
                r1 += __shfl_xor(r1, off, 64);
        }

        // ---- publish: single relaxed store per value, tag in mantissa LSBs
        if (l == 0) {
            float z1n = tanhf(xv1 + r1);
            if (even) z2h = tanhf(xv2 + r2);
            Z1hist[t * NH + h] = z1n;                       // cached, read post-kernel
            if (t < ND - 1) {
                unsigned zi = (__float_as_uint(z1n + z2h) & ~3u)
                            | ((unsigned)(t + 1) & 3u);
                AS(ZB + ((t + 1) & 1) * NH + h, zi);
                if (even) {
                    unsigned yi = (__float_as_uint(z2h) & ~3u)
                                | ((unsigned)((t >> 1) + 1) & 3u);
                    AS(Z2B + (((t >> 1) & 1) ^ 1) * NH + h, yi);
                }
            }
        }
    }
}

// ---------------- output projection, t-tiled: out[t] = tanh(z1[t]@Wout + b) --
__global__ void outproj(const float* __restrict__ Z1hist,
                        const float* __restrict__ Wout,
                        const float* __restrict__ bout,
                        float* __restrict__ out) {
    const int t0 = blockIdx.x * OTB;
    const int o  = threadIdx.x;

    __shared__ float lz[OTB][NH];          // 32 KB
    for (int idx = threadIdx.x; idx < OTB * NH; idx += 256) {
        int r = idx >> 10, c = idx & (NH - 1);
        lz[r][c] = Z1hist[(t0 + r) * NH + c];
    }
    __syncthreads();

    float acc[OTB];
    float bias = bout[o];
    #pragma unroll
    for (int r = 0; r < OTB; ++r) acc[r] = bias;

    for (int hh = 0; hh < NH; ++hh) {
        float wv = Wout[hh * NO + o];
        #pragma unroll
        for (int r = 0; r < OTB; ++r) acc[r] += lz[r][hh] * wv;
    }
    #pragma unroll
    for (int r = 0; r < OTB; ++r) out[(t0 + r) * NO + o] = tanhf(acc[r]);
}

extern "C" void kernel_launch(void* const* d_in, const int* in_sizes, int n_in,
                              void* d_out, int out_size, void* d_ws, size_t ws_size,
                              hipStream_t stream) {
    const float* x     = (const float*)d_in[0];
    const float* Win1  = (const float*)d_in[1];
    const float* b1    = (const float*)d_in[2];
    const float* Wr1   = (const float*)d_in[3];
    const float* Win2  = (const float*)d_in[4];
    const float* b2    = (const float*)d_in[5];
    const float* Wr2   = (const float*)d_in[6];
    const float* Wout  = (const float*)d_in[7];
    const float* bout  = (const float*)d_in[8];
    float* out = (float*)d_out;

    // workspace layout (4-byte units)
    unsigned* ws  = (unsigned*)d_ws;
    unsigned* ZB  = ws;                     // 2*NH  tagged z12 ping-pong
    unsigned* Z2B = ZB + 2 * NH;            // 2*NH  tagged z2 ping-pong
    float*    Z1h = (float*)(Z2B + 2 * NH); // ND*NH
    float*    X1  = Z1h + ND * NH;          // ND*NH
    float*    X2  = X1 + ND * NH;           // ND*NH

    // zero tagged buffers: tag 0 + value 0.0 == valid initial state for t=0
    hipMemsetAsync(ZB, 0, 4 * NH * sizeof(unsigned), stream);

    dim3 xg(NH / 256, ND / XTB, 2);
    xproj<<<xg, 256, 0, stream>>>(x, Win1, b1, Win2, b2, X1, X2);

    recur<<<RB, RT, 0, stream>>>(Wr1, Wr2, X1, X2, ZB, Z2B, Z1h);

    outproj<<<ND / OTB, NO, 0, stream>>>(Z1h, Wout, bout, out);
}